// Round 10
// baseline (448.282 us; speedup 1.0000x reference)
//
#include <hip/hip_runtime.h>
#include <math.h>

// ValueNetwork forward. conv2 via split-bf16 MFMA (3-pass hi/lo).
// Round-10: round-9 pipeline (429 us) + tail retile: k4a/k4c 512 blocks with
// 16-lane rows (serial chain halved), k5a/k5b grid (8,64) with 4-wide acc.
// ws layout (floats):
//  f    [64][32][128]        @ 0        (262144)
//  R    [64][3][64][128]     @ 262144   (1572864)
//  C    [64][3][64][128]     @ 1835008  (1572864)
//  D    [64][64][128][5]     @ 3407872  (2621440)
//  afa  [64][32][128]        @ 6029312  (262144)
//  smi  [64][128][64]        @ 6291456  (524288)
//  rh   [64][64][128]        @ 6823936  (524288)
//  hnm  [64][64]             @ 7348224  (4096)
//  Apack[2][9][4][64][8] u16 @ 7352320
//  so   [64][128][32]        @ 7376896  (262144)
//  se   [64][128]            @ 7641088  (8192)

typedef short bf16x8 __attribute__((ext_vector_type(8)));
typedef float f32x16 __attribute__((ext_vector_type(16)));

__device__ inline unsigned int bf16_rne(float x) {
  unsigned int u = __float_as_uint(x);
  return (u + 0x7fffu + ((u >> 16) & 1u)) >> 16;
}

// pack two f32 -> (bf16(a) | bf16(b)<<16) in one VALU op
__device__ inline unsigned int pk_bf16(float a, float b) {
  unsigned int r;
  asm("v_cvt_pk_bf16_f32 %0, %1, %2" : "=v"(r) : "v"(a), "v"(b));
  return r;
}

// tanh via fast exp; saturates correctly at +-inf
__device__ inline float fast_tanh(float x) {
  float e = __expf(2.f * x);
  return 1.f - 2.f / (e + 1.f);
}

__device__ inline float fast_sigmoid(float x) {
  return 1.f / (1.f + __expf(-x));
}

#define MF(A, B, Cc) __builtin_amdgcn_mfma_f32_32x32x16_bf16((A), (B), (Cc), 0, 0, 0)

// front MLP: agents(7) -> 64 relu -> 32 relu, f[b][c][n]
// blockIdx.y == 4: w_c2 packing (former k0), 576 items per x-block.
__global__ __launch_bounds__(128) void k1_front(
    const float* __restrict__ state, const float* __restrict__ w_in1,
    const float* __restrict__ b_in1, const float* __restrict__ w_in2,
    const float* __restrict__ b_in2, float* __restrict__ f,
    const float* __restrict__ w_c2, unsigned short* __restrict__ Apack) {
  int b = blockIdx.x, nq = blockIdx.y, t = threadIdx.x;
  if (nq == 4) {
    int base = b * 576;
    for (int idx = base + t; idx < base + 576; idx += 128) {
      int p = idx / 18432, rem = idx % 18432;
      int rx = rem >> 11, r2 = rem & 2047;
      int chunk = r2 >> 9, r3 = r2 & 511;
      int lane = r3 >> 3, i8 = r3 & 7;
      int o2 = lane & 31, k8 = lane >> 5;
      int cin = chunk * 16 + k8 * 8 + i8;
      float v = w_c2[(o2 * 64 + cin) * 9 + rx];
      unsigned int hi = bf16_rne(v);
      float hif = __uint_as_float(hi << 16);
      unsigned int lo = bf16_rne(v - hif);
      Apack[idx] = (unsigned short)(p ? lo : hi);
    }
    return;
  }
  int row = t >> 2, lane = t & 3;
  int n = nq * 32 + row;
  __shared__ float hs[32][66];
  const float* st = state + (b * 128 + n) * 13 + 6;
  float a[7];
#pragma unroll
  for (int k = 0; k < 7; k++) a[k] = st[k];
  for (int oi = 0; oi < 16; oi++) {
    int o = lane * 16 + oi;
    float acc = b_in1[o];
#pragma unroll
    for (int k = 0; k < 7; k++) acc += w_in1[o * 7 + k] * a[k];
    hs[row][o] = fmaxf(acc, 0.f);
  }
  __syncthreads();
  for (int ci = 0; ci < 8; ci++) {
    int c = lane * 8 + ci;
    float acc = b_in2[c];
#pragma unroll 8
    for (int k = 0; k < 64; k++) acc += w_in2[c * 64 + k] * hs[row][k];
    f[(b * 32 + c) * 128 + n] = fmaxf(acc, 0.f);
  }
}

// conv1 low-rank precompute. grid (o=64, b=64), 128 threads = i.
__global__ __launch_bounds__(128) void k2_pre(
    const float* __restrict__ f, const float* __restrict__ w_c1,
    float* __restrict__ R, float* __restrict__ C, float* __restrict__ D) {
  int o = blockIdx.x, b = blockIdx.y, t = threadIdx.x;
  __shared__ float fL[32 * 128];
  __shared__ float w1s[32 * 9];
  __shared__ float wrow[32 * 9];
  __shared__ float wcol[32 * 9];
  for (int idx = t; idx < 1024; idx += 128)
    ((float4*)fL)[idx] = ((const float4*)(f + b * 4096))[idx];
  for (int idx = t; idx < 288; idx += 128) w1s[idx] = w_c1[o * 288 + idx];
  __syncthreads();
  if (t < 32) {
    int c = t;
#pragma unroll
    for (int di = 0; di < 3; di++) {
      float w0 = w1s[c * 9 + di * 3 + 0], w1 = w1s[c * 9 + di * 3 + 1],
            w2 = w1s[c * 9 + di * 3 + 2];
      wrow[(c * 3 + di) * 3 + 0] = w1 + w2;
      wrow[(c * 3 + di) * 3 + 1] = w0 + w1 + w2;
      wrow[(c * 3 + di) * 3 + 2] = w0 + w1;
    }
#pragma unroll
    for (int dj = 0; dj < 3; dj++) {
      float w0 = w1s[c * 9 + 0 * 3 + dj], w1 = w1s[c * 9 + 1 * 3 + dj],
            w2 = w1s[c * 9 + 2 * 3 + dj];
      wcol[(c * 3 + dj) * 3 + 0] = w1 + w2;
      wcol[(c * 3 + dj) * 3 + 1] = w0 + w1 + w2;
      wcol[(c * 3 + dj) * 3 + 2] = w0 + w1;
    }
  }
  __syncthreads();
  int i = t;
  float r0 = 0, r1 = 0, r2 = 0, c0 = 0, c1 = 0, c2 = 0;
  float d0 = 0, d1 = 0, d2 = 0, d3 = 0, d4 = 0;
  for (int c = 0; c < 32; c++) {
    float fm = (i >= 1) ? fL[c * 128 + i - 1] : 0.f;
    float f0 = fL[c * 128 + i];
    float fp = (i < 127) ? fL[c * 128 + i + 1] : 0.f;
    const float* wr = &wrow[c * 9];
    r0 += fm * wr[0] + f0 * wr[3] + fp * wr[6];
    r1 += fm * wr[1] + f0 * wr[4] + fp * wr[7];
    r2 += fm * wr[2] + f0 * wr[5] + fp * wr[8];
    const float* wc = &wcol[c * 9];
    c0 += fm * wc[0] + f0 * wc[3] + fp * wc[6];
    c1 += fm * wc[1] + f0 * wc[4] + fp * wc[7];
    c2 += fm * wc[2] + f0 * wc[5] + fp * wc[8];
    const float* wp = &w1s[c * 9];
    d0 += fm * wp[2];
    d1 += fm * wp[1] + f0 * wp[5];
    d2 += fm * wp[0] + f0 * wp[4] + fp * wp[8];
    d3 += f0 * wp[3] + fp * wp[7];
    d4 += fp * wp[6];
  }
  R[((b * 3 + 0) * 64 + o) * 128 + i] = r0;
  R[((b * 3 + 1) * 64 + o) * 128 + i] = r1;
  R[((b * 3 + 2) * 64 + o) * 128 + i] = r2;
  C[((b * 3 + 0) * 64 + o) * 128 + i] = c0;
  C[((b * 3 + 1) * 64 + o) * 128 + i] = c1;
  C[((b * 3 + 2) * 64 + o) * 128 + i] = c2;
  float* dp = &D[((b * 64 + o) * 128 + i) * 5];
  dp[0] = d0; dp[1] = d1; dp[2] = d2; dp[3] = d3; dp[4] = d4;
}

// k3 (proven v3 + __expf): conv2 via MFMA + softmax + afa.
// grid (iblk=64, b=64), 512 thr. Dynamic LDS 81920 B.
__global__ __launch_bounds__(512, 4) void k3_conv2(
    const float* __restrict__ f, const float* __restrict__ R,
    const float* __restrict__ C, const float* __restrict__ D,
    const float* __restrict__ b_c1, const unsigned short* __restrict__ Apack,
    const float* __restrict__ b_c2, float* __restrict__ afa) {
  extern __shared__ unsigned short G[];  // 40960 u16 = 81920 B
  int iblk = blockIdx.x, b = blockIdx.y, t = threadIdx.x;
  int i0 = iblk * 2;
  int lane = t & 63, wv = t >> 6;
  int jt = wv & 3, cg = wv >> 2;
  int nn = lane & 31;
  int ccoff_half = (lane >> 5) * 8;
  const bf16x8* A8 = (const bf16x8*)Apack;
  bf16x8 zero8 = {0, 0, 0, 0, 0, 0, 0, 0};
  f32x16 acc0 = {0, 0, 0, 0, 0, 0, 0, 0, 0, 0, 0, 0, 0, 0, 0, 0};
  f32x16 acc1 = {0, 0, 0, 0, 0, 0, 0, 0, 0, 0, 0, 0, 0, 0, 0, 0};

  int ipl = t >> 7;
  int sh = (t >> 6) & 1;
  int cpr = (t >> 2) & 15;
  int q = t & 3;
  int j0r = q * 32;
  int ip = i0 - 1 + ipl;
  bool rowok = (ip >= 0 && ip <= 127);
  int ipc = ip < 0 ? 0 : (ip > 127 ? 127 : ip);
  int ic = (ipc == 0) ? 0 : ((ipc == 127) ? 2 : 1);

  // pass2 (tap overwrite): 320 threads cover 4 ipl x 5 jw x 16 ccp
  int ipl2 = t / 80;
  int rem2 = t % 80;
  int jw2 = rem2 >> 4;
  int ccp2 = rem2 & 15;
  int ip2 = i0 - 1 + ipl2;

  for (int half = 0; half < 2; half++) {
    if (half) __syncthreads();
    // ---- pass 1: relu(base - C), no taps ----
    {
      int cc = half * 32 + cpr * 2;
      float bias0 = b_c1[cc], bias1 = b_c1[cc + 1];
      float base0 = R[((b * 3 + 1) * 64 + cc) * 128 + ipc] + bias0;
      float base1 = R[((b * 3 + 1) * 64 + cc + 1) * 128 + ipc] + bias1;
      float r0v0 = 0, r0v1 = 0, r2v0 = 0, r2v1 = 0;
      if (q == 0 && sh == 0) {
        r0v0 = R[((b * 3 + 0) * 64 + cc) * 128 + ipc] + bias0;
        r0v1 = R[((b * 3 + 0) * 64 + cc + 1) * 128 + ipc] + bias1;
      }
      if (q == 3 && sh == 1) {
        r2v0 = R[((b * 3 + 2) * 64 + cc) * 128 + ipc] + bias0;
        r2v1 = R[((b * 3 + 2) * 64 + cc + 1) * 128 + ipc] + bias1;
      }
      const float* C0 = &C[((b * 3 + ic) * 64 + cc) * 128 + j0r];
      const float* C1 = C0 + 128;
      unsigned int gbase = (unsigned)((ipl * 128 + j0r) * 40 + 2 * cpr);
#pragma unroll
      for (int u = 0; u < 4; u++) {
        int s4 = (sh * 4 + u + q) & 7;  // rotation: 2-way write banks
        float4 c0 = ((const float4*)C0)[s4];
        float4 c1 = ((const float4*)C1)[s4];
        float v0[4], v1[4];
        v0[0] = base0 - c0.x; v0[1] = base0 - c0.y;
        v0[2] = base0 - c0.z; v0[3] = base0 - c0.w;
        v1[0] = base1 - c1.x; v1[1] = base1 - c1.y;
        v1[2] = base1 - c1.z; v1[3] = base1 - c1.w;
        if (q == 0 && s4 == 0) { v0[0] = r0v0 - c0.x; v1[0] = r0v1 - c1.x; }
        if (q == 3 && s4 == 7) { v0[3] = r2v0 - c0.w; v1[3] = r2v1 - c1.w; }
#pragma unroll
        for (int k = 0; k < 4; k++) {
          float a0 = rowok ? fmaxf(v0[k], 0.f) : 0.f;
          float a1 = rowok ? fmaxf(v1[k], 0.f) : 0.f;
          unsigned int hw = pk_bf16(a0, a1);
          float h0f = __uint_as_float(hw << 16);
          float h1f = __uint_as_float(hw & 0xffff0000u);
          unsigned int lw = pk_bf16(a0 - h0f, a1 - h1f);
          unsigned int off = gbase + (unsigned)((s4 * 4 + k) * 40);
          *(unsigned int*)&G[off] = hw;
          *(unsigned int*)&G[off + 20480] = lw;
        }
      }
    }
    __syncthreads();
    // ---- pass 2: overwrite tap columns j in [ip-2, ip+2] with base-C+D ----
    if (t < 320 && ip2 >= 0 && ip2 <= 127) {
      int j2 = ip2 - 2 + jw2;
      if (j2 >= 0 && j2 <= 127) {
        int cc2 = half * 32 + ccp2 * 2;
        int ic2 = (ip2 == 0) ? 0 : ((ip2 == 127) ? 2 : 1);
        int jsel = (j2 == 0) ? 0 : ((j2 == 127) ? 2 : 1);
        float b0 = b_c1[cc2], b1 = b_c1[cc2 + 1];
        float bb0 = R[((b * 3 + jsel) * 64 + cc2) * 128 + ip2] + b0;
        float bb1 = R[((b * 3 + jsel) * 64 + cc2 + 1) * 128 + ip2] + b1;
        float cv0 = C[((b * 3 + ic2) * 64 + cc2) * 128 + j2];
        float cv1 = C[((b * 3 + ic2) * 64 + cc2 + 1) * 128 + j2];
        float dv0 = D[((b * 64 + cc2) * 128 + ip2) * 5 + jw2];
        float dv1 = D[((b * 64 + cc2 + 1) * 128 + ip2) * 5 + jw2];
        float a0 = fmaxf(bb0 - cv0 + dv0, 0.f);
        float a1 = fmaxf(bb1 - cv1 + dv1, 0.f);
        unsigned int hw = pk_bf16(a0, a1);
        float h0f = __uint_as_float(hw << 16);
        float h1f = __uint_as_float(hw & 0xffff0000u);
        unsigned int lw = pk_bf16(a0 - h0f, a1 - h1f);
        unsigned int off = (unsigned)((ipl2 * 128 + j2) * 40 + 2 * ccp2);
        *(unsigned int*)&G[off] = hw;
        *(unsigned int*)&G[off + 20480] = lw;
      }
    }
    __syncthreads();
    // ---- MFMA: one chunk per wave-group ----
    {
      int chunk = half * 2 + cg;
      bf16x8 Ah[9], Al[9];
#pragma unroll
      for (int rx = 0; rx < 9; rx++) {
        Ah[rx] = A8[(rx * 4 + chunk) * 64 + lane];
        Al[rx] = A8[((9 + rx) * 4 + chunk) * 64 + lane];
      }
      int ccoff = cg * 16 + ccoff_half;
#pragma unroll
      for (int rowidx = 0; rowidx < 4; rowidx++) {
#pragma unroll
        for (int x = 0; x < 3; x++) {
          int imgj = jt * 32 + nn + x - 1;
          int ij = imgj < 0 ? 0 : (imgj > 127 ? 127 : imgj);
          int off = (rowidx * 128 + ij) * 40 + ccoff;
          bf16x8 bh = *(const bf16x8*)&G[off];
          bf16x8 bl = *(const bf16x8*)&G[off + 20480];
          if (imgj < 0 || imgj > 127) { bh = zero8; bl = zero8; }
          if (rowidx == 0) {
            acc0 = MF(Ah[x], bh, acc0);
            acc0 = MF(Ah[x], bl, acc0);
            acc0 = MF(Al[x], bh, acc0);
          } else if (rowidx == 1) {
            acc0 = MF(Ah[3 + x], bh, acc0);
            acc0 = MF(Ah[3 + x], bl, acc0);
            acc0 = MF(Al[3 + x], bh, acc0);
            acc1 = MF(Ah[x], bh, acc1);
            acc1 = MF(Ah[x], bl, acc1);
            acc1 = MF(Al[x], bh, acc1);
          } else if (rowidx == 2) {
            acc0 = MF(Ah[6 + x], bh, acc0);
            acc0 = MF(Ah[6 + x], bl, acc0);
            acc0 = MF(Al[6 + x], bh, acc0);
            acc1 = MF(Ah[3 + x], bh, acc1);
            acc1 = MF(Ah[3 + x], bl, acc1);
            acc1 = MF(Al[3 + x], bh, acc1);
          } else {
            acc1 = MF(Ah[6 + x], bh, acc1);
            acc1 = MF(Ah[6 + x], bl, acc1);
            acc1 = MF(Al[6 + x], bh, acc1);
          }
        }
      }
    }
  }
  __syncthreads();
  const int LSTR = 129;
  float* logits = (float*)G;
  float* fbuf = (float*)G + 64 * LSTR;
  int j = jt * 32 + nn;
  if (cg == 0) {
#pragma unroll
    for (int reg = 0; reg < 16; reg++) {
      int o2 = (reg & 3) + 8 * (reg >> 2) + 4 * (lane >> 5);
      logits[(0 * 32 + o2) * LSTR + j] = acc0[reg];
      logits[(1 * 32 + o2) * LSTR + j] = acc1[reg];
    }
  } else {
    for (int idx = t - 256; idx < 1024; idx += 256) {
      float4 v = ((const float4*)(f + b * 4096))[idx];
      int c = idx >> 5, s4f = idx & 31;
      float* dst = &fbuf[c * LSTR + s4f * 4];
      dst[0] = v.x; dst[1] = v.y; dst[2] = v.z; dst[3] = v.w;
    }
  }
  __syncthreads();
  if (cg == 1) {
#pragma unroll
    for (int reg = 0; reg < 16; reg++) {
      int o2 = (reg & 3) + 8 * (reg >> 2) + 4 * (lane >> 5);
      logits[(0 * 32 + o2) * LSTR + j] += acc0[reg];
      logits[(1 * 32 + o2) * LSTR + j] += acc1[reg];
    }
  }
  __syncthreads();
  {
    int i2 = t >> 8;
    int o2e = (t >> 3) & 31;
    int qe = t & 7;
    int rot = (qe * 2) & 15;
    const float* lrow = &logits[(i2 * 32 + o2e) * LSTR + qe * 16];
    float bias2 = b_c2[o2e];
    float vals[16];
    float mx = -3.0e38f;
#pragma unroll
    for (int s = 0; s < 16; s++) {
      vals[s] = lrow[(s + rot) & 15] + bias2;
      mx = fmaxf(mx, vals[s]);
    }
    mx = fmaxf(mx, __shfl_xor(mx, 1));
    mx = fmaxf(mx, __shfl_xor(mx, 2));
    mx = fmaxf(mx, __shfl_xor(mx, 4));
    float sum = 0.f;
#pragma unroll
    for (int s = 0; s < 16; s++) {
      vals[s] = __expf(vals[s] - mx);
      sum += vals[s];
    }
    sum += __shfl_xor(sum, 1);
    sum += __shfl_xor(sum, 2);
    sum += __shfl_xor(sum, 4);
    float inv = 1.f / sum;
    int gi = i0 + i2;
    float fi = fbuf[o2e * LSTR + gi];
    float part = 0.f;
#pragma unroll
    for (int s = 0; s < 16; s++) {
      int jj = qe * 16 + ((s + rot) & 15);
      float w = vals[s] * inv;
      part += w * (fi - fbuf[o2e * LSTR + jj]);
      if (jj == gi) part += w * fi;
    }
    part += __shfl_xor(part, 1);
    part += __shfl_xor(part, 2);
    part += __shfl_xor(part, 4);
    if (qe == 0) afa[(b * 32 + o2e) * 128 + gi] = part;
  }
}

// k4a v2: grid 512 blocks (b*8+nq), 256 thr, 16 rows x 16 lanes.
// Serial MAC chain halved vs v1 (430 vs 860).
__global__ __launch_bounds__(256) void k4a_sort(
    const float* __restrict__ state, const float* __restrict__ f,
    const float* __restrict__ afa, const float* __restrict__ w_ia1,
    const float* __restrict__ b_ia1, const float* __restrict__ w_ia2,
    const float* __restrict__ b_ia2, const float* __restrict__ w_s1,
    const float* __restrict__ b_s1, const float* __restrict__ w_s2,
    const float* __restrict__ b_s2, float* __restrict__ so_g) {
  int blk = blockIdx.x;
  int b = blk >> 3, nq = blk & 7;
  int t = threadIdx.x, row = t >> 4, lane = t & 15;
  int n = nq * 16 + row;
  __shared__ float bufA[16][40];
  __shared__ float bufB[16][72];
  {
    int c0 = lane * 2;
    float2 av = *(const float2*)&afa[b * 4096 + n * 32 + c0];
    bufA[row][c0 + 0] = f[b * 4096 + (c0 + 0) * 128 + n] + av.x;
    bufA[row][c0 + 1] = f[b * 4096 + (c0 + 1) * 128 + n] + av.y;
  }
  __syncthreads();
#pragma unroll
  for (int oi = 0; oi < 4; oi++) {
    int o = lane * 4 + oi;
    float a = b_ia1[o];
#pragma unroll 8
    for (int c = 0; c < 32; c++) a += w_ia1[o * 32 + c] * bufA[row][c];
    bufB[row][o] = fmaxf(a, 0.f);
  }
  __syncthreads();
  {
    float r0[2];
#pragma unroll
    for (int oi = 0; oi < 2; oi++) {
      int o = lane * 2 + oi;
      float a = b_ia2[o];
#pragma unroll 8
      for (int k = 0; k < 64; k++) a += w_ia2[o * 64 + k] * bufB[row][k];
      r0[oi] = a;
    }
    __syncthreads();
#pragma unroll
    for (int oi = 0; oi < 2; oi++) bufA[row][lane * 2 + oi] = r0[oi];
    if (lane == 0) {
#pragma unroll
      for (int k = 0; k < 6; k++)
        bufA[row][32 + k] = state[(b * 128 + n) * 13 + k];
    }
  }
  __syncthreads();
#pragma unroll
  for (int oi = 0; oi < 4; oi++) {
    int o = lane * 4 + oi;
    float a = b_s1[o];
#pragma unroll 2
    for (int k = 0; k < 38; k++) a += w_s1[o * 38 + k] * bufA[row][k];
    bufB[row][o] = fmaxf(a, 0.f);
  }
  __syncthreads();
#pragma unroll
  for (int oi = 0; oi < 2; oi++) {
    int o = lane * 2 + oi;
    float a = b_s2[o];
#pragma unroll 8
    for (int k = 0; k < 64; k++) a += w_s2[o * 64 + k] * bufB[row][k];
    so_g[(b * 128 + n) * 32 + o] = a;
  }
}

// k4c v2: grid 512 blocks, 256 thr, 16 rows x 16 lanes.
__global__ __launch_bounds__(256) void k4c_attn(
    const float* __restrict__ so_g, const float* __restrict__ w_a1,
    const float* __restrict__ b_a1, const float* __restrict__ w_a2,
    const float* __restrict__ b_a2, const float* __restrict__ w_a3,
    const float* __restrict__ b_a3, float* __restrict__ smi,
    float* __restrict__ se_g) {
  int blk = blockIdx.x;
  int b = blk >> 3, nq = blk & 7;
  int t = threadIdx.x, row = t >> 4, lane = t & 15;
  int n = nq * 16 + row;
  __shared__ float bufA[16][72];
  __shared__ float bufB[16][72];
  __shared__ float gred[8][32];
  __shared__ float gs_s[32];
  {
    int c = t & 31, grp = t >> 5;
    float s = 0.f;
#pragma unroll 4
    for (int k = 0; k < 16; k++) s += so_g[(b * 128 + grp * 16 + k) * 32 + c];
    gred[grp][c] = s;
  }
  {
    int c0 = lane * 2;
    float2 sv = *(const float2*)&so_g[(b * 128 + n) * 32 + c0];
    *(float2*)&bufA[row][c0] = sv;
    *(float2*)&smi[b * 8192 + n * 64 + c0] = sv;
  }
  __syncthreads();
  if (t < 32) {
    float s = 0.f;
#pragma unroll
    for (int g = 0; g < 8; g++) s += gred[g][t];
    gs_s[t] = s * (1.f / 128.f);
  }
  __syncthreads();
  {
    int c0 = lane * 2;
    float2 gv = *(const float2*)&gs_s[c0];
    *(float2*)&bufA[row][32 + c0] = gv;
    *(float2*)&smi[b * 8192 + n * 64 + 32 + c0] = gv;
  }
  __syncthreads();
#pragma unroll
  for (int oi = 0; oi < 4; oi++) {
    int o = lane * 4 + oi;
    float a = b_a1[o];
#pragma unroll 8
    for (int k = 0; k < 64; k++) a += w_a1[o * 64 + k] * bufA[row][k];
    bufB[row][o] = fmaxf(a, 0.f);
  }
  __syncthreads();
  float ps = 0.f;
#pragma unroll
  for (int oi = 0; oi < 2; oi++) {
    int o = lane * 2 + oi;
    float a = b_a2[o];
#pragma unroll 8
    for (int k = 0; k < 64; k++) a += w_a2[o * 64 + k] * bufB[row][k];
    ps += w_a3[o] * fmaxf(a, 0.f);
  }
  for (int d = 8; d >= 1; d >>= 1) ps += __shfl_xor(ps, d, 16);
  if (lane == 0) {
    float sc = ps + b_a3[0];
    se_g[b * 128 + n] = (sc != 0.f) ? __expf(sc) : 0.f;
  }
}

// GRU r-gate v2: grid (8, 64), 8 c per block, 4-wide acc.
__global__ __launch_bounds__(256) void k5a_r(
    const float* __restrict__ smi, const float* __restrict__ se_g,
    const float* __restrict__ w_r, float* __restrict__ rh) {
  int cch = blockIdx.x, b = blockIdx.y, t = threadIdx.x;
  __shared__ float smi_s[128 * 65];
  __shared__ float wts_s[128];
  __shared__ float invs_s;
  for (int idx = t; idx < 8192; idx += 256) {
    int n = idx >> 6, k = idx & 63;
    smi_s[n * 65 + k] = smi[b * 8192 + idx];
  }
  if (t < 128) wts_s[t] = se_g[b * 128 + t];
  __syncthreads();
  if (t < 64) {
    float s2 = wts_s[t] + wts_s[t + 64];
    for (int d = 32; d >= 1; d >>= 1) s2 += __shfl_xor(s2, d);
    if (t == 0) invs_s = 1.f / s2;
  }
  __syncthreads();
  if (t < 128) wts_s[t] *= invs_s;
  __syncthreads();
  int c = cch * 8 + (t >> 5), l = t & 31;
  float accs[4];
#pragma unroll
  for (int m = 0; m < 4; m++) accs[m] = 0.f;
  const float* wr = &w_r[c * 128];
  for (int k = 0; k < 64; k++) {
    float wv = wr[k];
#pragma unroll
    for (int m = 0; m < 4; m++) accs[m] += wv * smi_s[(l + 32 * m) * 65 + k];
  }
  for (int c2 = 0; c2 < 64; c2++) {
    float wv = wr[64 + c2];
    float g0 = wts_s[2 * c2], g1 = wts_s[2 * c2 + 1];
#pragma unroll
    for (int m = 0; m < 4; m++) {
      int nb = m >> 1, nl = l + 32 * (m & 1);
      accs[m] += wv * ((nb ? g1 : g0) * smi_s[(2 * c2 + nb) * 65 + nl]);
    }
  }
#pragma unroll
  for (int m = 0; m < 4; m++) {
    int n = l + 32 * m;
    float r = fast_sigmoid(accs[m]);
    rh[(b * 64 + c) * 128 + n] = r * smi_s[n * 65 + c];
  }
}

// GRU z, q, hn, mean v2: grid (8, 64), 8 o per block, 4-wide acc.
__global__ __launch_bounds__(256) void k5b_gru(
    const float* __restrict__ smi, const float* __restrict__ se_g,
    const float* __restrict__ rh, const float* __restrict__ w_z,
    const float* __restrict__ w_q, float* __restrict__ hnm) {
  int och = blockIdx.x, b = blockIdx.y, t = threadIdx.x;
  __shared__ float smi_s[128 * 65];
  __shared__ float wts_s[128];
  __shared__ float invs_s;
  for (int idx = t; idx < 8192; idx += 256) {
    int n = idx >> 6, k = idx & 63;
    smi_s[n * 65 + k] = smi[b * 8192 + idx];
  }
  if (t < 128) wts_s[t] = se_g[b * 128 + t];
  __syncthreads();
  if (t < 64) {
    float s2 = wts_s[t] + wts_s[t + 64];
    for (int d = 32; d >= 1; d >>= 1) s2 += __shfl_xor(s2, d);
    if (t == 0) invs_s = 1.f / s2;
  }
  __syncthreads();
  if (t < 128) wts_s[t] *= invs_s;
  __syncthreads();
  int o = och * 8 + (t >> 5), l = t & 31;
  float az[4], aq[4];
#pragma unroll
  for (int m = 0; m < 4; m++) { az[m] = 0.f; aq[m] = 0.f; }
  const float* wz = &w_z[o * 128];
  const float* wq = &w_q[o * 128];
  const float* rhb = rh + b * 8192;
  for (int k = 0; k < 64; k++) {
    float wv = wz[k];
#pragma unroll
    for (int m = 0; m < 4; m++) az[m] += wv * smi_s[(l + 32 * m) * 65 + k];
  }
  for (int c = 0; c < 64; c++) {
    float wv = wq[c];
#pragma unroll
    for (int m = 0; m < 4; m++) aq[m] += wv * rhb[c * 128 + l + 32 * m];
  }
  for (int c2 = 0; c2 < 64; c2++) {
    float wvz = wz[64 + c2], wvq = wq[64 + c2];
    float g0 = wts_s[2 * c2], g1 = wts_s[2 * c2 + 1];
#pragma unroll
    for (int m = 0; m < 4; m++) {
      int nb = m >> 1, nl = l + 32 * (m & 1);
      float gin = (nb ? g1 : g0) * smi_s[(2 * c2 + nb) * 65 + nl];
      az[m] += wvz * gin;
      aq[m] += wvq * gin;
    }
  }
  float part = 0.f;
#pragma unroll
  for (int m = 0; m < 4; m++) {
    int n = l + 32 * m;
    float z = fast_sigmoid(az[m]);
    float q = fast_tanh(aq[m]);
    float h0 = smi_s[n * 65 + o];
    part += (1.f - z) * h0 + z * q;
  }
  for (int d = 16; d >= 1; d >>= 1) part += __shfl_xor(part, d, 32);
  if (l == 0) hnm[b * 64 + o] = part * (1.f / 128.f);
}

__global__ __launch_bounds__(128, 1) void k6_head(
    const float* __restrict__ state, const float* __restrict__ hnm,
    const float* __restrict__ w_m1, const float* __restrict__ b_m1,
    const float* __restrict__ w_m2, const float* __restrict__ b_m2,
    const float* __restrict__ w_m3, const float* __restrict__ b_m3,
    float* __restrict__ out) {
  int b = blockIdx.x, t = threadIdx.x;
  __shared__ float joint[70];
  __shared__ float m1s[128];
  __shared__ float red[64];
  if (t < 6) joint[t] = state[b * 1664 + t];
  if (t < 64) joint[6 + t] = hnm[b * 64 + t];
  __syncthreads();
  float a = b_m1[t];
#pragma unroll 2
  for (int k = 0; k < 70; k++) a += w_m1[t * 70 + k] * joint[k];
  m1s[t] = fmaxf(a, 0.f);
  __syncthreads();
  if (t < 64) {
    float a2 = b_m2[t];
#pragma unroll 8
    for (int k = 0; k < 128; k++) a2 += w_m2[t * 128 + k] * m1s[k];
    red[t] = fmaxf(a2, 0.f) * w_m3[t];
  }
  __syncthreads();
  for (int s = 32; s >= 1; s >>= 1) {
    if (t < s) red[t] += red[t + s];
    __syncthreads();
  }
  if (t == 0) out[b] = red[0] + b_m3[0];
}

extern "C" void kernel_launch(void* const* d_in, const int* in_sizes, int n_in,
                              void* d_out, int out_size, void* d_ws, size_t ws_size,
                              hipStream_t stream) {
  const float* state = (const float*)d_in[0];
  const float* w_in1 = (const float*)d_in[1];
  const float* b_in1 = (const float*)d_in[2];
  const float* w_in2 = (const float*)d_in[3];
  const float* b_in2 = (const float*)d_in[4];
  const float* w_c1  = (const float*)d_in[5];
  const float* b_c1  = (const float*)d_in[6];
  const float* w_c2  = (const float*)d_in[7];
  const float* b_c2  = (const float*)d_in[8];
  const float* w_ia1 = (const float*)d_in[9];
  const float* b_ia1 = (const float*)d_in[10];
  const float* w_ia2 = (const float*)d_in[11];
  const float* b_ia2 = (const float*)d_in[12];
  const float* w_s1  = (const float*)d_in[13];
  const float* b_s1  = (const float*)d_in[14];
  const float* w_s2  = (const float*)d_in[15];
  const float* b_s2  = (const float*)d_in[16];
  const float* w_a1  = (const float*)d_in[17];
  const float* b_a1  = (const float*)d_in[18];
  const float* w_a2  = (const float*)d_in[19];
  const float* b_a2  = (const float*)d_in[20];
  const float* w_a3  = (const float*)d_in[21];
  const float* b_a3  = (const float*)d_in[22];
  const float* w_z   = (const float*)d_in[23];
  const float* w_r   = (const float*)d_in[24];
  const float* w_q   = (const float*)d_in[25];
  const float* w_m1  = (const float*)d_in[26];
  const float* b_m1  = (const float*)d_in[27];
  const float* w_m2  = (const float*)d_in[28];
  const float* b_m2  = (const float*)d_in[29];
  const float* w_m3  = (const float*)d_in[30];
  const float* b_m3  = (const float*)d_in[31];
  float* ws    = (float*)d_ws;
  float* f_    = ws;
  float* R_    = ws + 262144;
  float* C_    = ws + 1835008;
  float* D_    = ws + 3407872;
  float* afa_  = ws + 6029312;
  float* smi_  = ws + 6291456;
  float* rh_   = ws + 6823936;
  float* hnm_  = ws + 7348224;
  unsigned short* Apack_ = (unsigned short*)(ws + 7352320);
  float* so_   = ws + 7376896;
  float* se_   = ws + 7641088;
  float* out   = (float*)d_out;

  k1_front<<<dim3(64, 5), 128, 0, stream>>>(state, w_in1, b_in1, w_in2, b_in2,
                                            f_, w_c2, Apack_);
  k2_pre<<<dim3(64, 64), 128, 0, stream>>>(f_, w_c1, R_, C_, D_);
  k3_conv2<<<dim3(64, 64), 512, 81920, stream>>>(f_, R_, C_, D_, b_c1, Apack_,
                                                 b_c2, afa_);
  k4a_sort<<<512, 256, 0, stream>>>(state, f_, afa_, w_ia1, b_ia1, w_ia2, b_ia2,
                                    w_s1, b_s1, w_s2, b_s2, so_);
  k4c_attn<<<512, 256, 0, stream>>>(so_, w_a1, b_a1, w_a2, b_a2, w_a3, b_a3,
                                    smi_, se_);
  k5a_r<<<dim3(8, 64), 256, 0, stream>>>(smi_, se_, w_r, rh_);
  k5b_gru<<<dim3(8, 64), 256, 0, stream>>>(smi_, se_, rh_, w_z, w_q, hnm_);
  k6_head<<<64, 128, 0, stream>>>(state, hnm_, w_m1, b_m1, w_m2, b_m2, w_m3,
                                  b_m3, out);
}

// Round 11
// 426.876 us; speedup vs baseline: 1.0501x; 1.0501x over previous
//
#include <hip/hip_runtime.h>
#include <math.h>

// ValueNetwork forward. conv2 via split-bf16 MFMA (3-pass hi/lo).
// FINAL (round-9 best, 429 us): 8-launch pipeline. k3 = v3 structure
// (bank-conflict-free epilogue, wave-split chunks, tap-overwrite pass,
// __expf softmax); tail = proven per-phase kernels with fast activations.
// Structural alternatives bracketed and rejected: mega-fusion (grid=64,
// 275 us), cooperative grid.sync (314 us), k3 quarter-staging (342 us),
// tail retile (448 us).
// ws layout (floats):
//  f    [64][32][128]        @ 0        (262144)
//  R    [64][3][64][128]     @ 262144   (1572864)
//  C    [64][3][64][128]     @ 1835008  (1572864)
//  D    [64][64][128][5]     @ 3407872  (2621440)
//  afa  [64][32][128]        @ 6029312  (262144)
//  smi  [64][128][64]        @ 6291456  (524288)
//  rh   [64][64][128]        @ 6823936  (524288)
//  hnm  [64][64]             @ 7348224  (4096)
//  Apack[2][9][4][64][8] u16 @ 7352320
//  so   [64][128][32]        @ 7376896  (262144)
//  se   [64][128]            @ 7641088  (8192)

typedef short bf16x8 __attribute__((ext_vector_type(8)));
typedef float f32x16 __attribute__((ext_vector_type(16)));

__device__ inline unsigned int bf16_rne(float x) {
  unsigned int u = __float_as_uint(x);
  return (u + 0x7fffu + ((u >> 16) & 1u)) >> 16;
}

// pack two f32 -> (bf16(a) | bf16(b)<<16) in one VALU op
__device__ inline unsigned int pk_bf16(float a, float b) {
  unsigned int r;
  asm("v_cvt_pk_bf16_f32 %0, %1, %2" : "=v"(r) : "v"(a), "v"(b));
  return r;
}

// tanh via fast exp; saturates correctly at +-inf
__device__ inline float fast_tanh(float x) {
  float e = __expf(2.f * x);
  return 1.f - 2.f / (e + 1.f);
}

__device__ inline float fast_sigmoid(float x) {
  return 1.f / (1.f + __expf(-x));
}

#define MF(A, B, Cc) __builtin_amdgcn_mfma_f32_32x32x16_bf16((A), (B), (Cc), 0, 0, 0)

// front MLP: agents(7) -> 64 relu -> 32 relu, f[b][c][n]
// blockIdx.y == 4: w_c2 packing (former k0), 576 items per x-block.
__global__ __launch_bounds__(128) void k1_front(
    const float* __restrict__ state, const float* __restrict__ w_in1,
    const float* __restrict__ b_in1, const float* __restrict__ w_in2,
    const float* __restrict__ b_in2, float* __restrict__ f,
    const float* __restrict__ w_c2, unsigned short* __restrict__ Apack) {
  int b = blockIdx.x, nq = blockIdx.y, t = threadIdx.x;
  if (nq == 4) {
    int base = b * 576;
    for (int idx = base + t; idx < base + 576; idx += 128) {
      int p = idx / 18432, rem = idx % 18432;
      int rx = rem >> 11, r2 = rem & 2047;
      int chunk = r2 >> 9, r3 = r2 & 511;
      int lane = r3 >> 3, i8 = r3 & 7;
      int o2 = lane & 31, k8 = lane >> 5;
      int cin = chunk * 16 + k8 * 8 + i8;
      float v = w_c2[(o2 * 64 + cin) * 9 + rx];
      unsigned int hi = bf16_rne(v);
      float hif = __uint_as_float(hi << 16);
      unsigned int lo = bf16_rne(v - hif);
      Apack[idx] = (unsigned short)(p ? lo : hi);
    }
    return;
  }
  int row = t >> 2, lane = t & 3;
  int n = nq * 32 + row;
  __shared__ float hs[32][66];
  const float* st = state + (b * 128 + n) * 13 + 6;
  float a[7];
#pragma unroll
  for (int k = 0; k < 7; k++) a[k] = st[k];
  for (int oi = 0; oi < 16; oi++) {
    int o = lane * 16 + oi;
    float acc = b_in1[o];
#pragma unroll
    for (int k = 0; k < 7; k++) acc += w_in1[o * 7 + k] * a[k];
    hs[row][o] = fmaxf(acc, 0.f);
  }
  __syncthreads();
  for (int ci = 0; ci < 8; ci++) {
    int c = lane * 8 + ci;
    float acc = b_in2[c];
#pragma unroll 8
    for (int k = 0; k < 64; k++) acc += w_in2[c * 64 + k] * hs[row][k];
    f[(b * 32 + c) * 128 + n] = fmaxf(acc, 0.f);
  }
}

// conv1 low-rank precompute. grid (o=64, b=64), 128 threads = i.
__global__ __launch_bounds__(128) void k2_pre(
    const float* __restrict__ f, const float* __restrict__ w_c1,
    float* __restrict__ R, float* __restrict__ C, float* __restrict__ D) {
  int o = blockIdx.x, b = blockIdx.y, t = threadIdx.x;
  __shared__ float fL[32 * 128];
  __shared__ float w1s[32 * 9];
  __shared__ float wrow[32 * 9];
  __shared__ float wcol[32 * 9];
  for (int idx = t; idx < 1024; idx += 128)
    ((float4*)fL)[idx] = ((const float4*)(f + b * 4096))[idx];
  for (int idx = t; idx < 288; idx += 128) w1s[idx] = w_c1[o * 288 + idx];
  __syncthreads();
  if (t < 32) {
    int c = t;
#pragma unroll
    for (int di = 0; di < 3; di++) {
      float w0 = w1s[c * 9 + di * 3 + 0], w1 = w1s[c * 9 + di * 3 + 1],
            w2 = w1s[c * 9 + di * 3 + 2];
      wrow[(c * 3 + di) * 3 + 0] = w1 + w2;
      wrow[(c * 3 + di) * 3 + 1] = w0 + w1 + w2;
      wrow[(c * 3 + di) * 3 + 2] = w0 + w1;
    }
#pragma unroll
    for (int dj = 0; dj < 3; dj++) {
      float w0 = w1s[c * 9 + 0 * 3 + dj], w1 = w1s[c * 9 + 1 * 3 + dj],
            w2 = w1s[c * 9 + 2 * 3 + dj];
      wcol[(c * 3 + dj) * 3 + 0] = w1 + w2;
      wcol[(c * 3 + dj) * 3 + 1] = w0 + w1 + w2;
      wcol[(c * 3 + dj) * 3 + 2] = w0 + w1;
    }
  }
  __syncthreads();
  int i = t;
  float r0 = 0, r1 = 0, r2 = 0, c0 = 0, c1 = 0, c2 = 0;
  float d0 = 0, d1 = 0, d2 = 0, d3 = 0, d4 = 0;
  for (int c = 0; c < 32; c++) {
    float fm = (i >= 1) ? fL[c * 128 + i - 1] : 0.f;
    float f0 = fL[c * 128 + i];
    float fp = (i < 127) ? fL[c * 128 + i + 1] : 0.f;
    const float* wr = &wrow[c * 9];
    r0 += fm * wr[0] + f0 * wr[3] + fp * wr[6];
    r1 += fm * wr[1] + f0 * wr[4] + fp * wr[7];
    r2 += fm * wr[2] + f0 * wr[5] + fp * wr[8];
    const float* wc = &wcol[c * 9];
    c0 += fm * wc[0] + f0 * wc[3] + fp * wc[6];
    c1 += fm * wc[1] + f0 * wc[4] + fp * wc[7];
    c2 += fm * wc[2] + f0 * wc[5] + fp * wc[8];
    const float* wp = &w1s[c * 9];
    d0 += fm * wp[2];
    d1 += fm * wp[1] + f0 * wp[5];
    d2 += fm * wp[0] + f0 * wp[4] + fp * wp[8];
    d3 += f0 * wp[3] + fp * wp[7];
    d4 += fp * wp[6];
  }
  R[((b * 3 + 0) * 64 + o) * 128 + i] = r0;
  R[((b * 3 + 1) * 64 + o) * 128 + i] = r1;
  R[((b * 3 + 2) * 64 + o) * 128 + i] = r2;
  C[((b * 3 + 0) * 64 + o) * 128 + i] = c0;
  C[((b * 3 + 1) * 64 + o) * 128 + i] = c1;
  C[((b * 3 + 2) * 64 + o) * 128 + i] = c2;
  float* dp = &D[((b * 64 + o) * 128 + i) * 5];
  dp[0] = d0; dp[1] = d1; dp[2] = d2; dp[3] = d3; dp[4] = d4;
}

// k3 (proven v3 + __expf): conv2 via MFMA + softmax + afa.
// grid (iblk=64, b=64), 512 thr. Dynamic LDS 81920 B.
__global__ __launch_bounds__(512, 4) void k3_conv2(
    const float* __restrict__ f, const float* __restrict__ R,
    const float* __restrict__ C, const float* __restrict__ D,
    const float* __restrict__ b_c1, const unsigned short* __restrict__ Apack,
    const float* __restrict__ b_c2, float* __restrict__ afa) {
  extern __shared__ unsigned short G[];  // 40960 u16 = 81920 B
  int iblk = blockIdx.x, b = blockIdx.y, t = threadIdx.x;
  int i0 = iblk * 2;
  int lane = t & 63, wv = t >> 6;
  int jt = wv & 3, cg = wv >> 2;
  int nn = lane & 31;
  int ccoff_half = (lane >> 5) * 8;
  const bf16x8* A8 = (const bf16x8*)Apack;
  bf16x8 zero8 = {0, 0, 0, 0, 0, 0, 0, 0};
  f32x16 acc0 = {0, 0, 0, 0, 0, 0, 0, 0, 0, 0, 0, 0, 0, 0, 0, 0};
  f32x16 acc1 = {0, 0, 0, 0, 0, 0, 0, 0, 0, 0, 0, 0, 0, 0, 0, 0};

  int ipl = t >> 7;
  int sh = (t >> 6) & 1;
  int cpr = (t >> 2) & 15;
  int q = t & 3;
  int j0r = q * 32;
  int ip = i0 - 1 + ipl;
  bool rowok = (ip >= 0 && ip <= 127);
  int ipc = ip < 0 ? 0 : (ip > 127 ? 127 : ip);
  int ic = (ipc == 0) ? 0 : ((ipc == 127) ? 2 : 1);

  // pass2 (tap overwrite): 320 threads cover 4 ipl x 5 jw x 16 ccp
  int ipl2 = t / 80;
  int rem2 = t % 80;
  int jw2 = rem2 >> 4;
  int ccp2 = rem2 & 15;
  int ip2 = i0 - 1 + ipl2;

  for (int half = 0; half < 2; half++) {
    if (half) __syncthreads();
    // ---- pass 1: relu(base - C), no taps ----
    {
      int cc = half * 32 + cpr * 2;
      float bias0 = b_c1[cc], bias1 = b_c1[cc + 1];
      float base0 = R[((b * 3 + 1) * 64 + cc) * 128 + ipc] + bias0;
      float base1 = R[((b * 3 + 1) * 64 + cc + 1) * 128 + ipc] + bias1;
      float r0v0 = 0, r0v1 = 0, r2v0 = 0, r2v1 = 0;
      if (q == 0 && sh == 0) {
        r0v0 = R[((b * 3 + 0) * 64 + cc) * 128 + ipc] + bias0;
        r0v1 = R[((b * 3 + 0) * 64 + cc + 1) * 128 + ipc] + bias1;
      }
      if (q == 3 && sh == 1) {
        r2v0 = R[((b * 3 + 2) * 64 + cc) * 128 + ipc] + bias0;
        r2v1 = R[((b * 3 + 2) * 64 + cc + 1) * 128 + ipc] + bias1;
      }
      const float* C0 = &C[((b * 3 + ic) * 64 + cc) * 128 + j0r];
      const float* C1 = C0 + 128;
      unsigned int gbase = (unsigned)((ipl * 128 + j0r) * 40 + 2 * cpr);
#pragma unroll
      for (int u = 0; u < 4; u++) {
        int s4 = (sh * 4 + u + q) & 7;  // rotation: 2-way write banks
        float4 c0 = ((const float4*)C0)[s4];
        float4 c1 = ((const float4*)C1)[s4];
        float v0[4], v1[4];
        v0[0] = base0 - c0.x; v0[1] = base0 - c0.y;
        v0[2] = base0 - c0.z; v0[3] = base0 - c0.w;
        v1[0] = base1 - c1.x; v1[1] = base1 - c1.y;
        v1[2] = base1 - c1.z; v1[3] = base1 - c1.w;
        if (q == 0 && s4 == 0) { v0[0] = r0v0 - c0.x; v1[0] = r0v1 - c1.x; }
        if (q == 3 && s4 == 7) { v0[3] = r2v0 - c0.w; v1[3] = r2v1 - c1.w; }
#pragma unroll
        for (int k = 0; k < 4; k++) {
          float a0 = rowok ? fmaxf(v0[k], 0.f) : 0.f;
          float a1 = rowok ? fmaxf(v1[k], 0.f) : 0.f;
          unsigned int hw = pk_bf16(a0, a1);
          float h0f = __uint_as_float(hw << 16);
          float h1f = __uint_as_float(hw & 0xffff0000u);
          unsigned int lw = pk_bf16(a0 - h0f, a1 - h1f);
          unsigned int off = gbase + (unsigned)((s4 * 4 + k) * 40);
          *(unsigned int*)&G[off] = hw;
          *(unsigned int*)&G[off + 20480] = lw;
        }
      }
    }
    __syncthreads();
    // ---- pass 2: overwrite tap columns j in [ip-2, ip+2] with base-C+D ----
    if (t < 320 && ip2 >= 0 && ip2 <= 127) {
      int j2 = ip2 - 2 + jw2;
      if (j2 >= 0 && j2 <= 127) {
        int cc2 = half * 32 + ccp2 * 2;
        int ic2 = (ip2 == 0) ? 0 : ((ip2 == 127) ? 2 : 1);
        int jsel = (j2 == 0) ? 0 : ((j2 == 127) ? 2 : 1);
        float b0 = b_c1[cc2], b1 = b_c1[cc2 + 1];
        float bb0 = R[((b * 3 + jsel) * 64 + cc2) * 128 + ip2] + b0;
        float bb1 = R[((b * 3 + jsel) * 64 + cc2 + 1) * 128 + ip2] + b1;
        float cv0 = C[((b * 3 + ic2) * 64 + cc2) * 128 + j2];
        float cv1 = C[((b * 3 + ic2) * 64 + cc2 + 1) * 128 + j2];
        float dv0 = D[((b * 64 + cc2) * 128 + ip2) * 5 + jw2];
        float dv1 = D[((b * 64 + cc2 + 1) * 128 + ip2) * 5 + jw2];
        float a0 = fmaxf(bb0 - cv0 + dv0, 0.f);
        float a1 = fmaxf(bb1 - cv1 + dv1, 0.f);
        unsigned int hw = pk_bf16(a0, a1);
        float h0f = __uint_as_float(hw << 16);
        float h1f = __uint_as_float(hw & 0xffff0000u);
        unsigned int lw = pk_bf16(a0 - h0f, a1 - h1f);
        unsigned int off = (unsigned)((ipl2 * 128 + j2) * 40 + 2 * ccp2);
        *(unsigned int*)&G[off] = hw;
        *(unsigned int*)&G[off + 20480] = lw;
      }
    }
    __syncthreads();
    // ---- MFMA: one chunk per wave-group ----
    {
      int chunk = half * 2 + cg;
      bf16x8 Ah[9], Al[9];
#pragma unroll
      for (int rx = 0; rx < 9; rx++) {
        Ah[rx] = A8[(rx * 4 + chunk) * 64 + lane];
        Al[rx] = A8[((9 + rx) * 4 + chunk) * 64 + lane];
      }
      int ccoff = cg * 16 + ccoff_half;
#pragma unroll
      for (int rowidx = 0; rowidx < 4; rowidx++) {
#pragma unroll
        for (int x = 0; x < 3; x++) {
          int imgj = jt * 32 + nn + x - 1;
          int ij = imgj < 0 ? 0 : (imgj > 127 ? 127 : imgj);
          int off = (rowidx * 128 + ij) * 40 + ccoff;
          bf16x8 bh = *(const bf16x8*)&G[off];
          bf16x8 bl = *(const bf16x8*)&G[off + 20480];
          if (imgj < 0 || imgj > 127) { bh = zero8; bl = zero8; }
          if (rowidx == 0) {
            acc0 = MF(Ah[x], bh, acc0);
            acc0 = MF(Ah[x], bl, acc0);
            acc0 = MF(Al[x], bh, acc0);
          } else if (rowidx == 1) {
            acc0 = MF(Ah[3 + x], bh, acc0);
            acc0 = MF(Ah[3 + x], bl, acc0);
            acc0 = MF(Al[3 + x], bh, acc0);
            acc1 = MF(Ah[x], bh, acc1);
            acc1 = MF(Ah[x], bl, acc1);
            acc1 = MF(Al[x], bh, acc1);
          } else if (rowidx == 2) {
            acc0 = MF(Ah[6 + x], bh, acc0);
            acc0 = MF(Ah[6 + x], bl, acc0);
            acc0 = MF(Al[6 + x], bh, acc0);
            acc1 = MF(Ah[3 + x], bh, acc1);
            acc1 = MF(Ah[3 + x], bl, acc1);
            acc1 = MF(Al[3 + x], bh, acc1);
          } else {
            acc1 = MF(Ah[6 + x], bh, acc1);
            acc1 = MF(Ah[6 + x], bl, acc1);
            acc1 = MF(Al[6 + x], bh, acc1);
          }
        }
      }
    }
  }
  __syncthreads();
  const int LSTR = 129;
  float* logits = (float*)G;
  float* fbuf = (float*)G + 64 * LSTR;
  int j = jt * 32 + nn;
  if (cg == 0) {
#pragma unroll
    for (int reg = 0; reg < 16; reg++) {
      int o2 = (reg & 3) + 8 * (reg >> 2) + 4 * (lane >> 5);
      logits[(0 * 32 + o2) * LSTR + j] = acc0[reg];
      logits[(1 * 32 + o2) * LSTR + j] = acc1[reg];
    }
  } else {
    for (int idx = t - 256; idx < 1024; idx += 256) {
      float4 v = ((const float4*)(f + b * 4096))[idx];
      int c = idx >> 5, s4f = idx & 31;
      float* dst = &fbuf[c * LSTR + s4f * 4];
      dst[0] = v.x; dst[1] = v.y; dst[2] = v.z; dst[3] = v.w;
    }
  }
  __syncthreads();
  if (cg == 1) {
#pragma unroll
    for (int reg = 0; reg < 16; reg++) {
      int o2 = (reg & 3) + 8 * (reg >> 2) + 4 * (lane >> 5);
      logits[(0 * 32 + o2) * LSTR + j] += acc0[reg];
      logits[(1 * 32 + o2) * LSTR + j] += acc1[reg];
    }
  }
  __syncthreads();
  {
    int i2 = t >> 8;
    int o2e = (t >> 3) & 31;
    int qe = t & 7;
    int rot = (qe * 2) & 15;
    const float* lrow = &logits[(i2 * 32 + o2e) * LSTR + qe * 16];
    float bias2 = b_c2[o2e];
    float vals[16];
    float mx = -3.0e38f;
#pragma unroll
    for (int s = 0; s < 16; s++) {
      vals[s] = lrow[(s + rot) & 15] + bias2;
      mx = fmaxf(mx, vals[s]);
    }
    mx = fmaxf(mx, __shfl_xor(mx, 1));
    mx = fmaxf(mx, __shfl_xor(mx, 2));
    mx = fmaxf(mx, __shfl_xor(mx, 4));
    float sum = 0.f;
#pragma unroll
    for (int s = 0; s < 16; s++) {
      vals[s] = __expf(vals[s] - mx);
      sum += vals[s];
    }
    sum += __shfl_xor(sum, 1);
    sum += __shfl_xor(sum, 2);
    sum += __shfl_xor(sum, 4);
    float inv = 1.f / sum;
    int gi = i0 + i2;
    float fi = fbuf[o2e * LSTR + gi];
    float part = 0.f;
#pragma unroll
    for (int s = 0; s < 16; s++) {
      int jj = qe * 16 + ((s + rot) & 15);
      float w = vals[s] * inv;
      part += w * (fi - fbuf[o2e * LSTR + jj]);
      if (jj == gi) part += w * fi;
    }
    part += __shfl_xor(part, 1);
    part += __shfl_xor(part, 2);
    part += __shfl_xor(part, 4);
    if (qe == 0) afa[(b * 32 + o2e) * 128 + gi] = part;
  }
}

// k4a: per (b,n): x -> h1 -> ia||self -> s1 -> so. grid 256 blocks, 256 thr.
__global__ __launch_bounds__(256) void k4a_sort(
    const float* __restrict__ state, const float* __restrict__ f,
    const float* __restrict__ afa, const float* __restrict__ w_ia1,
    const float* __restrict__ b_ia1, const float* __restrict__ w_ia2,
    const float* __restrict__ b_ia2, const float* __restrict__ w_s1,
    const float* __restrict__ b_s1, const float* __restrict__ w_s2,
    const float* __restrict__ b_s2, float* __restrict__ so_g) {
  int blk = blockIdx.x;
  int b = blk >> 2, nq = blk & 3;
  int t = threadIdx.x, row = t >> 3, lane = t & 7;
  int n = nq * 32 + row;
  __shared__ float bufA[32][40];
  __shared__ float bufB[32][72];
  {
    int c0 = lane * 4;
    float4 av = *(const float4*)&afa[b * 4096 + n * 32 + c0];
    bufA[row][c0 + 0] = f[b * 4096 + (c0 + 0) * 128 + n] + av.x;
    bufA[row][c0 + 1] = f[b * 4096 + (c0 + 1) * 128 + n] + av.y;
    bufA[row][c0 + 2] = f[b * 4096 + (c0 + 2) * 128 + n] + av.z;
    bufA[row][c0 + 3] = f[b * 4096 + (c0 + 3) * 128 + n] + av.w;
  }
  __syncthreads();
#pragma unroll
  for (int oi = 0; oi < 8; oi++) {
    int o = lane * 8 + oi;
    float a = b_ia1[o];
#pragma unroll 8
    for (int c = 0; c < 32; c++) a += w_ia1[o * 32 + c] * bufA[row][c];
    bufB[row][o] = fmaxf(a, 0.f);
  }
  __syncthreads();
  {
    float r0[4];
#pragma unroll
    for (int oi = 0; oi < 4; oi++) {
      int o = lane * 4 + oi;
      float a = b_ia2[o];
#pragma unroll 8
      for (int k = 0; k < 64; k++) a += w_ia2[o * 64 + k] * bufB[row][k];
      r0[oi] = a;
    }
    __syncthreads();
#pragma unroll
    for (int oi = 0; oi < 4; oi++) bufA[row][lane * 4 + oi] = r0[oi];
    if (lane == 0) {
#pragma unroll
      for (int k = 0; k < 6; k++)
        bufA[row][32 + k] = state[(b * 128 + n) * 13 + k];
    }
  }
  __syncthreads();
#pragma unroll
  for (int oi = 0; oi < 8; oi++) {
    int o = lane * 8 + oi;
    float a = b_s1[o];
#pragma unroll 2
    for (int k = 0; k < 38; k++) a += w_s1[o * 38 + k] * bufA[row][k];
    bufB[row][o] = fmaxf(a, 0.f);
  }
  __syncthreads();
#pragma unroll
  for (int oi = 0; oi < 4; oi++) {
    int o = lane * 4 + oi;
    float a = b_s2[o];
#pragma unroll 8
    for (int k = 0; k < 64; k++) a += w_s2[o * 64 + k] * bufB[row][k];
    so_g[(b * 128 + n) * 32 + o] = a;
  }
}

// k4c: gstate (in-block) + attn MLP -> se, smi
__global__ __launch_bounds__(256) void k4c_attn(
    const float* __restrict__ so_g, const float* __restrict__ w_a1,
    const float* __restrict__ b_a1, const float* __restrict__ w_a2,
    const float* __restrict__ b_a2, const float* __restrict__ w_a3,
    const float* __restrict__ b_a3, float* __restrict__ smi,
    float* __restrict__ se_g) {
  int blk = blockIdx.x;
  int b = blk >> 2, nq = blk & 3;
  int t = threadIdx.x, row = t >> 3, lane = t & 7;
  int n = nq * 32 + row;
  __shared__ float bufA[32][72];
  __shared__ float bufB[32][72];
  __shared__ float gred[8][32];
  __shared__ float gs_s[32];
  {
    int c = t & 31, grp = t >> 5;
    float s = 0.f;
#pragma unroll 4
    for (int k = 0; k < 16; k++) s += so_g[(b * 128 + grp * 16 + k) * 32 + c];
    gred[grp][c] = s;
  }
  {
    int c0 = lane * 4;
    float4 sv = *(const float4*)&so_g[(b * 128 + n) * 32 + c0];
    *(float4*)&bufA[row][c0] = sv;
    *(float4*)&smi[b * 8192 + n * 64 + c0] = sv;
  }
  __syncthreads();
  if (t < 32) {
    float s = 0.f;
#pragma unroll
    for (int g = 0; g < 8; g++) s += gred[g][t];
    gs_s[t] = s * (1.f / 128.f);
  }
  __syncthreads();
  {
    int c0 = lane * 4;
    float4 gv = *(const float4*)&gs_s[c0];
    *(float4*)&bufA[row][32 + c0] = gv;
    *(float4*)&smi[b * 8192 + n * 64 + 32 + c0] = gv;
  }
  __syncthreads();
#pragma unroll
  for (int oi = 0; oi < 8; oi++) {
    int o = lane * 8 + oi;
    float a = b_a1[o];
#pragma unroll 8
    for (int k = 0; k < 64; k++) a += w_a1[o * 64 + k] * bufA[row][k];
    bufB[row][o] = fmaxf(a, 0.f);
  }
  __syncthreads();
  float ps = 0.f;
#pragma unroll
  for (int oi = 0; oi < 4; oi++) {
    int o = lane * 4 + oi;
    float a = b_a2[o];
#pragma unroll 8
    for (int k = 0; k < 64; k++) a += w_a2[o * 64 + k] * bufB[row][k];
    ps += w_a3[o] * fmaxf(a, 0.f);
  }
  for (int d = 4; d >= 1; d >>= 1) ps += __shfl_xor(ps, d, 8);
  if (lane == 0) {
    float sc = ps + b_a3[0];
    se_g[b * 128 + n] = (sc != 0.f) ? __expf(sc) : 0.f;
  }
}

// GRU r-gate (wts computed in-block from se_g)
__global__ __launch_bounds__(256) void k5a_r(
    const float* __restrict__ smi, const float* __restrict__ se_g,
    const float* __restrict__ w_r, float* __restrict__ rh) {
  int cch = blockIdx.x, b = blockIdx.y, t = threadIdx.x;
  __shared__ float smi_s[128 * 65];
  __shared__ float wts_s[128];
  __shared__ float invs_s;
  for (int idx = t; idx < 8192; idx += 256) {
    int n = idx >> 6, k = idx & 63;
    smi_s[n * 65 + k] = smi[b * 8192 + idx];
  }
  if (t < 128) wts_s[t] = se_g[b * 128 + t];
  __syncthreads();
  if (t < 64) {
    float s2 = wts_s[t] + wts_s[t + 64];
    for (int d = 32; d >= 1; d >>= 1) s2 += __shfl_xor(s2, d);
    if (t == 0) invs_s = 1.f / s2;
  }
  __syncthreads();
  if (t < 128) wts_s[t] *= invs_s;
  __syncthreads();
  int c = cch * 16 + (t >> 4), l = t & 15;
  float accs[8];
#pragma unroll
  for (int m = 0; m < 8; m++) accs[m] = 0.f;
  const float* wr = &w_r[c * 128];
  for (int k = 0; k < 64; k++) {
    float wv = wr[k];
#pragma unroll
    for (int m = 0; m < 8; m++) accs[m] += wv * smi_s[(l + 16 * m) * 65 + k];
  }
  for (int c2 = 0; c2 < 64; c2++) {
    float wv = wr[64 + c2];
    float g0 = wts_s[2 * c2], g1 = wts_s[2 * c2 + 1];
#pragma unroll
    for (int m = 0; m < 8; m++) {
      int nb = (m >> 2) & 1, nl = l + 16 * (m & 3);
      accs[m] += wv * ((nb ? g1 : g0) * smi_s[(2 * c2 + nb) * 65 + nl]);
    }
  }
#pragma unroll
  for (int m = 0; m < 8; m++) {
    int n = l + 16 * m;
    float r = fast_sigmoid(accs[m]);
    rh[(b * 64 + c) * 128 + n] = r * smi_s[n * 65 + c];
  }
}

// GRU z, q, hn, mean over n (wts in-block)
__global__ __launch_bounds__(256) void k5b_gru(
    const float* __restrict__ smi, const float* __restrict__ se_g,
    const float* __restrict__ rh, const float* __restrict__ w_z,
    const float* __restrict__ w_q, float* __restrict__ hnm) {
  int och = blockIdx.x, b = blockIdx.y, t = threadIdx.x;
  __shared__ float smi_s[128 * 65];
  __shared__ float wts_s[128];
  __shared__ float invs_s;
  for (int idx = t; idx < 8192; idx += 256) {
    int n = idx >> 6, k = idx & 63;
    smi_s[n * 65 + k] = smi[b * 8192 + idx];
  }
  if (t < 128) wts_s[t] = se_g[b * 128 + t];
  __syncthreads();
  if (t < 64) {
    float s2 = wts_s[t] + wts_s[t + 64];
    for (int d = 32; d >= 1; d >>= 1) s2 += __shfl_xor(s2, d);
    if (t == 0) invs_s = 1.f / s2;
  }
  __syncthreads();
  if (t < 128) wts_s[t] *= invs_s;
  __syncthreads();
  int o = och * 16 + (t >> 4), l = t & 15;
  float az[8], aq[8];
#pragma unroll
  for (int m = 0; m < 8; m++) { az[m] = 0.f; aq[m] = 0.f; }
  const float* wz = &w_z[o * 128];
  const float* wq = &w_q[o * 128];
  const float* rhb = rh + b * 8192;
  for (int k = 0; k < 64; k++) {
    float wv = wz[k];
#pragma unroll
    for (int m = 0; m < 8; m++) az[m] += wv * smi_s[(l + 16 * m) * 65 + k];
  }
  for (int c = 0; c < 64; c++) {
    float wv = wq[c];
#pragma unroll
    for (int m = 0; m < 8; m++) aq[m] += wv * rhb[c * 128 + l + 16 * m];
  }
  for (int c2 = 0; c2 < 64; c2++) {
    float wvz = wz[64 + c2], wvq = wq[64 + c2];
    float g0 = wts_s[2 * c2], g1 = wts_s[2 * c2 + 1];
#pragma unroll
    for (int m = 0; m < 8; m++) {
      int nb = (m >> 2) & 1, nl = l + 16 * (m & 3);
      float gin = (nb ? g1 : g0) * smi_s[(2 * c2 + nb) * 65 + nl];
      az[m] += wvz * gin;
      aq[m] += wvq * gin;
    }
  }
  float part = 0.f;
#pragma unroll
  for (int m = 0; m < 8; m++) {
    int n = l + 16 * m;
    float z = fast_sigmoid(az[m]);
    float q = fast_tanh(aq[m]);
    float h0 = smi_s[n * 65 + o];
    part += (1.f - z) * h0 + z * q;
  }
  for (int d = 8; d >= 1; d >>= 1) part += __shfl_xor(part, d, 16);
  if (l == 0) hnm[b * 64 + o] = part * (1.f / 128.f);
}

__global__ __launch_bounds__(128, 1) void k6_head(
    const float* __restrict__ state, const float* __restrict__ hnm,
    const float* __restrict__ w_m1, const float* __restrict__ b_m1,
    const float* __restrict__ w_m2, const float* __restrict__ b_m2,
    const float* __restrict__ w_m3, const float* __restrict__ b_m3,
    float* __restrict__ out) {
  int b = blockIdx.x, t = threadIdx.x;
  __shared__ float joint[70];
  __shared__ float m1s[128];
  __shared__ float red[64];
  if (t < 6) joint[t] = state[b * 1664 + t];
  if (t < 64) joint[6 + t] = hnm[b * 64 + t];
  __syncthreads();
  float a = b_m1[t];
#pragma unroll 2
  for (int k = 0; k < 70; k++) a += w_m1[t * 70 + k] * joint[k];
  m1s[t] = fmaxf(a, 0.f);
  __syncthreads();
  if (t < 64) {
    float a2 = b_m2[t];
#pragma unroll 8
    for (int k = 0; k < 128; k++) a2 += w_m2[t * 128 + k] * m1s[k];
    red[t] = fmaxf(a2, 0.f) * w_m3[t];
  }
  __syncthreads();
  for (int s = 32; s >= 1; s >>= 1) {
    if (t < s) red[t] += red[t + s];
    __syncthreads();
  }
  if (t == 0) out[b] = red[0] + b_m3[0];
}

extern "C" void kernel_launch(void* const* d_in, const int* in_sizes, int n_in,
                              void* d_out, int out_size, void* d_ws, size_t ws_size,
                              hipStream_t stream) {
  const float* state = (const float*)d_in[0];
  const float* w_in1 = (const float*)d_in[1];
  const float* b_in1 = (const float*)d_in[2];
  const float* w_in2 = (const float*)d_in[3];
  const float* b_in2 = (const float*)d_in[4];
  const float* w_c1  = (const float*)d_in[5];
  const float* b_c1  = (const float*)d_in[6];
  const float* w_c2  = (const float*)d_in[7];
  const float* b_c2  = (const float*)d_in[8];
  const float* w_ia1 = (const float*)d_in[9];
  const float* b_ia1 = (const float*)d_in[10];
  const float* w_ia2 = (const float*)d_in[11];
  const float* b_ia2 = (const float*)d_in[12];
  const float* w_s1  = (const float*)d_in[13];
  const float* b_s1  = (const float*)d_in[14];
  const float* w_s2  = (const float*)d_in[15];
  const float* b_s2  = (const float*)d_in[16];
  const float* w_a1  = (const float*)d_in[17];
  const float* b_a1  = (const float*)d_in[18];
  const float* w_a2  = (const float*)d_in[19];
  const float* b_a2  = (const float*)d_in[20];
  const float* w_a3  = (const float*)d_in[21];
  const float* b_a3  = (const float*)d_in[22];
  const float* w_z   = (const float*)d_in[23];
  const float* w_r   = (const float*)d_in[24];
  const float* w_q   = (const float*)d_in[25];
  const float* w_m1  = (const float*)d_in[26];
  const float* b_m1  = (const float*)d_in[27];
  const float* w_m2  = (const float*)d_in[28];
  const float* b_m2  = (const float*)d_in[29];
  const float* w_m3  = (const float*)d_in[30];
  const float* b_m3  = (const float*)d_in[31];
  float* ws    = (float*)d_ws;
  float* f_    = ws;
  float* R_    = ws + 262144;
  float* C_    = ws + 1835008;
  float* D_    = ws + 3407872;
  float* afa_  = ws + 6029312;
  float* smi_  = ws + 6291456;
  float* rh_   = ws + 6823936;
  float* hnm_  = ws + 7348224;
  unsigned short* Apack_ = (unsigned short*)(ws + 7352320);
  float* so_   = ws + 7376896;
  float* se_   = ws + 7641088;
  float* out   = (float*)d_out;

  k1_front<<<dim3(64, 5), 128, 0, stream>>>(state, w_in1, b_in1, w_in2, b_in2,
                                            f_, w_c2, Apack_);
  k2_pre<<<dim3(64, 64), 128, 0, stream>>>(f_, w_c1, R_, C_, D_);
  k3_conv2<<<dim3(64, 64), 512, 81920, stream>>>(f_, R_, C_, D_, b_c1, Apack_,
                                                 b_c2, afa_);
  k4a_sort<<<256, 256, 0, stream>>>(state, f_, afa_, w_ia1, b_ia1, w_ia2, b_ia2,
                                    w_s1, b_s1, w_s2, b_s2, so_);
  k4c_attn<<<256, 256, 0, stream>>>(so_, w_a1, b_a1, w_a2, b_a2, w_a3, b_a3,
                                    smi_, se_);
  k5a_r<<<dim3(4, 64), 256, 0, stream>>>(smi_, se_, w_r, rh_);
  k5b_gru<<<dim3(4, 64), 256, 0, stream>>>(smi_, se_, rh_, w_z, w_q, hnm_);
  k6_head<<<64, 128, 0, stream>>>(state, hnm_, w_m1, b_m1, w_m2, b_m2, w_m3,
                                  b_m3, out);
}